// Round 2
// baseline (991.061 us; speedup 1.0000x reference)
//
#include <hip/hip_runtime.h>
#include <cstddef>

// FlowNetC correlation: B=8, C=256, H=96, W=128, D=21 (disp stride 2, max 20)
// out[b, iy*21+ix, y, x] = (1/C) * sum_c in1[b,c,y,x] * in2[b,c,y+2*(iy-10),x+2*(ix-10)]
// (zero outside bounds)
//
// Design: one block = (b, 16-row y-tile, iy); all 21 ix per block.
// Parity-split in2 LDS (disp stride 2 => same-parity taps are dense in
// half-index space). in1 read directly from global (each element used once
// per block per channel => LDS staging would be pure overhead).
// Per chunk/thread: 336 FMA, 288 B LDS traffic = 0.86 B/FMA (budget 1.0).

#define CC 256
#define HH 96
#define WW 128
#define DD 21
#define TY 16          // rows per block
#define CK 2           // channels per LDS chunk
#define NCHUNK (CC / CK)

#define S2 92          // LDS floats per (ck,row,parity) plane: 10 pad + 64 + 18 pad
#define S2_TOT (CK * TY * 2 * S2)   // 5888 floats = 23.5 KB

__global__ __launch_bounds__(256, 2) void corr_kernel(const float* __restrict__ in1,
                                                      const float* __restrict__ in2,
                                                      float* __restrict__ out)
{
    __shared__ float s2[S2_TOT];

    // 1008 blocks = 8 XCDs * 126. Bijective XCD-contiguous swizzle; iy fastest
    // so the 21 blocks sharing one (b,y-tile)'s in1/in2 rows land on one XCD's L2.
    const int bx = blockIdx.x;
    const int logical = (bx & 7) * 126 + (bx >> 3);
    const int iy = logical % DD;
    const int t  = logical / DD;        // 0..47
    const int y0 = (t % 6) * TY;
    const int b  = t / 6;

    const int tid = threadIdx.x;
    const int g = tid & 7;              // pixel-group within (row,parity)
    const int p = (tid >> 3) & 1;       // parity
    const int r = tid >> 4;             // row 0..15
    const int u0 = g * 8;               // first half-position (8 per thread)

    // ---- pre-zero in2 LDS: x-pads and OOB rows stay zero forever ----
    for (int i = tid; i < S2_TOT; i += 256) s2[i] = 0.0f;

    const float* base1 = in1 + (size_t)b * CC * HH * WW;
    const float* base2 = in2 + (size_t)b * CC * HH * WW;

    // ---- in2 staging precompute: 4 float4 loads per thread per chunk ----
    int o2[4], l2a[4];
    bool ok2[4];
#pragma unroll
    for (int i = 0; i < 4; ++i) {
        const int v   = i * 256 + tid;      // float4 id, 0..1023
        const int ck  = v >> 9;             // 0..1
        const int rem = v & 511;
        const int row = rem >> 5;           // 0..15
        const int xq  = rem & 31;           // float4 column
        const int y2  = y0 + row + 2 * iy - 20;
        ok2[i] = ((unsigned)y2 < (unsigned)HH);
        o2[i] = (ck * HH + (ok2[i] ? y2 : 0)) * WW + xq * 4;
        l2a[i] = ((ck * TY + row) * 2) * S2 + 10 + xq * 2;   // even plane; odd = +S2
    }

    // in1 per-thread base: row (y0+r), x = 2*u0 + p, channel 0
    const float* a_ptr = base1 + (size_t)(y0 + r) * WW + 2 * u0 + p;

    float acc[8][DD];
#pragma unroll
    for (int pi = 0; pi < 8; ++pi)
#pragma unroll
        for (int k = 0; k < DD; ++k) acc[pi][k] = 0.0f;

    // ---- main loop over channel chunks ----
    for (int m = 0; m < NCHUNK; ++m) {
        __syncthreads();   // previous compute done reading LDS (covers pre-zero too)

        // stage in2 (parity-split; skip OOB rows -> stay zero)
#pragma unroll
        for (int i = 0; i < 4; ++i) {
            if (ok2[i]) {
                const float4 t4 = *(const float4*)(base2 + o2[i]);
                *(float2*)&s2[l2a[i]]      = make_float2(t4.x, t4.z);
                *(float2*)&s2[l2a[i] + S2] = make_float2(t4.y, t4.w);
            }
            o2[i] += CK * HH * WW;
        }

        // in1 loads for both channels of this chunk (independent of barrier;
        // latency hides under the staging barrier + other block's compute)
        float a0[8], a1[8];
#pragma unroll
        for (int pi = 0; pi < 8; ++pi) {
            a0[pi] = a_ptr[2 * pi];
            a1[pi] = a_ptr[(size_t)HH * WW + 2 * pi];
        }
        a_ptr += (size_t)CK * HH * WW;

        __syncthreads();   // staged data visible

        // compute: 2 channels x 8 px x 21 dx
#pragma unroll
        for (int ck = 0; ck < CK; ++ck) {
            const float* plane = s2 + ((ck * TY + r) * 2 + p) * S2 + u0;
            const float* a = (ck == 0) ? a0 : a1;

            float v[28];
#pragma unroll
            for (int j = 0; j < 7; ++j) {
                const float4 t4 = *(const float4*)(plane + 4 * j);
                v[4 * j + 0] = t4.x; v[4 * j + 1] = t4.y;
                v[4 * j + 2] = t4.z; v[4 * j + 3] = t4.w;
            }

#pragma unroll
            for (int pi = 0; pi < 8; ++pi)
#pragma unroll
                for (int k = 0; k < DD; ++k)
                    acc[pi][k] = fmaf(a[pi], v[pi + k], acc[pi][k]);
        }
    }

    // ---- epilogue: scale + store ----
    const float sc = 1.0f / (float)CC;
    const int xbase = 2 * u0 + p;
    const size_t hw = (size_t)HH * WW;
    size_t ob = ((size_t)b * (DD * DD) + (size_t)(iy * DD)) * hw
              + (size_t)(y0 + r) * WW + xbase;
#pragma unroll
    for (int k = 0; k < DD; ++k) {
#pragma unroll
        for (int pi = 0; pi < 8; ++pi)
            out[ob + 2 * pi] = acc[pi][k] * sc;
        ob += hw;
    }
}

extern "C" void kernel_launch(void* const* d_in, const int* in_sizes, int n_in,
                              void* d_out, int out_size, void* d_ws, size_t ws_size,
                              hipStream_t stream)
{
    const float* in1 = (const float*)d_in[0];
    const float* in2 = (const float*)d_in[1];
    float* out = (float*)d_out;
    (void)in_sizes; (void)n_in; (void)d_ws; (void)ws_size; (void)out_size;

    corr_kernel<<<dim3(8 * 6 * DD), dim3(256), 0, stream>>>(in1, in2, out);
}